// Round 2
// baseline (934.200 us; speedup 1.0000x reference)
//
#include <hip/hip_runtime.h>
#include <hip/hip_bf16.h>

// Problem constants
#define OUT_F 11008   // N
#define IN_F  4096    // K
#define M_DIM 4096    // 4 * 1024

typedef __attribute__((ext_vector_type(8))) short bf16x8;          // MFMA A/B frag
typedef __attribute__((ext_vector_type(4))) float f32x4;           // MFMA C/D frag
typedef __attribute__((ext_vector_type(8))) unsigned short us8;    // 16B of bf16 bits

// ---------------------------------------------------------------------------
// Kernel 1: x fp32 -> bf16 (RNE), 8 elems/thread
// ---------------------------------------------------------------------------
__device__ __forceinline__ unsigned short f2bf_rne(float f) {
    unsigned u = __builtin_bit_cast(unsigned, f);
    u += 0x7fffu + ((u >> 16) & 1u);
    return (unsigned short)(u >> 16);
}

__global__ void cvt_x_kernel(const float* __restrict__ x,
                             unsigned short* __restrict__ xb) {
    size_t i = ((size_t)blockIdx.x * blockDim.x + threadIdx.x) * 8;
    float4 a = *(const float4*)(x + i);
    float4 b = *(const float4*)(x + i + 4);
    us8 o;
    o[0] = f2bf_rne(a.x); o[1] = f2bf_rne(a.y);
    o[2] = f2bf_rne(a.z); o[3] = f2bf_rne(a.w);
    o[4] = f2bf_rne(b.x); o[5] = f2bf_rne(b.y);
    o[6] = f2bf_rne(b.z); o[7] = f2bf_rne(b.w);
    *(us8*)(xb + i) = o;
}

// ---------------------------------------------------------------------------
// Kernel 2: unpack 2-bit weights -> bf16 [OUT_F][IN_F] (B^T layout).
// field t in {0,1,2,3} -> t-1 in {-1,0,1,2}; bf16 LUT {0xBF80,0,0x3F80,0x4000}
// 4 packed ints (16 weights) per thread.
// ---------------------------------------------------------------------------
__global__ void unpack_w_kernel(const int* __restrict__ pw,
                                unsigned short* __restrict__ wb) {
    size_t i = (size_t)blockIdx.x * blockDim.x + threadIdx.x;
    int4 v = ((const int4*)pw)[i];
    const unsigned long long LUT = 0x40003F800000BF80ull;
    us8 o0, o1;
#pragma unroll
    for (int j = 0; j < 4; j++) {
        o0[j]     = (unsigned short)(LUT >> (((v.x >> (2 * j)) & 3) * 16));
        o0[4 + j] = (unsigned short)(LUT >> (((v.y >> (2 * j)) & 3) * 16));
        o1[j]     = (unsigned short)(LUT >> (((v.z >> (2 * j)) & 3) * 16));
        o1[4 + j] = (unsigned short)(LUT >> (((v.w >> (2 * j)) & 3) * 16));
    }
    ((us8*)wb)[i * 2]     = o0;
    ((us8*)wb)[i * 2 + 1] = o1;
}

// ---------------------------------------------------------------------------
// Kernel 3: bf16 GEMM, C[M][N] = A[M][K] * B[N][K]^T * scale
// 128x128 tile, BK=32, 4 waves 2x2 (64x64 each = 4x4 MFMA 16x16x32 tiles).
//
// LDS layout is SEGMENT-MAJOR: entry (seg, row) at byte (seg*128+row)*16,
// seg = k-quad (16B of k), row = m/n row. The frag read for quad q reads
// 16 consecutive 16B entries -> 256 contiguous bytes -> conflict-free.
// Staging instruction b (b=0..7) fills entries [b*64, b*64+63]:
//   seg = b>>1, row = (b&1)*64 + lane  (global_load_lds: base + lane*16).
// ---------------------------------------------------------------------------
__global__ __launch_bounds__(256) void gemm_kernel(
    const unsigned short* __restrict__ A,   // [M_DIM][IN_F] bf16 bits
    const unsigned short* __restrict__ B,   // [OUT_F][IN_F] bf16 bits
    float* __restrict__ C,                  // [M_DIM][OUT_F]
    const float* __restrict__ scale_ptr) {
    constexpr int K = IN_F;
    constexpr int N = OUT_F;
    constexpr int NB_N = 86;   // N / 128
    constexpr int NB_M = 32;   // M / 128

    __shared__ unsigned short sA[128 * 32]; // 8 KB, seg-major
    __shared__ unsigned short sB[128 * 32]; // 8 KB, seg-major

    const int tid  = threadIdx.x;
    const int wave = tid >> 6;
    const int lane = tid & 63;

    // Column-group swizzle (8 bn per group) for L2 reuse of A across bn.
    const int lin = blockIdx.y * gridDim.x + blockIdx.x;
    const int grp = lin >> 8;                  // / (8*32)
    const int rem = lin & 255;
    const int gw  = (grp * 8 + 8 <= NB_N) ? 8 : (NB_N - grp * 8);
    const int bn  = grp * 8 + rem % gw;
    const int bm  = rem / gw;
    (void)NB_M;

    const int wm = (wave >> 1) * 64;
    const int wn = (wave & 1) * 64;

    const unsigned short* Ag = A + (size_t)bm * 128 * K;
    const unsigned short* Bg = B + (size_t)bn * 128 * K;

    f32x4 acc[4][4];
#pragma unroll
    for (int i = 0; i < 4; i++)
#pragma unroll
        for (int j = 0; j < 4; j++) acc[i][j] = (f32x4){0.f, 0.f, 0.f, 0.f};

    const int quad = lane >> 4;   // k-seg for frags, row-quad for C
    const int mrow = lane & 15;   // m (A) / n (B) / col (C)

    for (int k0 = 0; k0 < K; k0 += 32) {
        __syncthreads();  // previous tile's frag reads done before overwrite
#pragma unroll
        for (int c = 0; c < 2; c++) {
            const int b   = wave * 2 + c;
            const int seg = b >> 1;
            const int row = ((b & 1) << 6) + lane;
            __builtin_amdgcn_global_load_lds(
                (const __attribute__((address_space(1))) void*)(Ag + (size_t)row * K + k0 + seg * 8),
                (__attribute__((address_space(3))) void*)(sA + b * 512),
                16, 0, 0);
        }
#pragma unroll
        for (int c = 0; c < 2; c++) {
            const int b   = wave * 2 + c;
            const int seg = b >> 1;
            const int row = ((b & 1) << 6) + lane;
            __builtin_amdgcn_global_load_lds(
                (const __attribute__((address_space(1))) void*)(Bg + (size_t)row * K + k0 + seg * 8),
                (__attribute__((address_space(3))) void*)(sB + b * 512),
                16, 0, 0);
        }
        __syncthreads();  // staging drained

        bf16x8 af[4], bfg[4];
#pragma unroll
        for (int t = 0; t < 4; t++) {
            af[t]  = *(const bf16x8*)(sA + (quad * 128 + wm + t * 16 + mrow) * 8);
            bfg[t] = *(const bf16x8*)(sB + (quad * 128 + wn + t * 16 + mrow) * 8);
        }
#pragma unroll
        for (int i = 0; i < 4; i++)
#pragma unroll
            for (int j = 0; j < 4; j++)
                acc[i][j] = __builtin_amdgcn_mfma_f32_16x16x32_bf16(
                    af[i], bfg[j], acc[i][j], 0, 0, 0);
    }

    // Epilogue: C/D layout col=lane&15, row=quad*4+reg
    const float scale = *scale_ptr;
    float* Cg = C + (size_t)bm * 128 * N + (size_t)bn * 128;
#pragma unroll
    for (int i = 0; i < 4; i++) {
#pragma unroll
        for (int j = 0; j < 4; j++) {
#pragma unroll
            for (int r = 0; r < 4; r++) {
                const int row = wm + i * 16 + quad * 4 + r;
                const int col = wn + j * 16 + mrow;
                Cg[(size_t)row * N + col] = acc[i][j][r] * scale;
            }
        }
    }
}

// ---------------------------------------------------------------------------
// Launch
// ---------------------------------------------------------------------------
extern "C" void kernel_launch(void* const* d_in, const int* in_sizes, int n_in,
                              void* d_out, int out_size, void* d_ws, size_t ws_size,
                              hipStream_t stream) {
    const float* x   = (const float*)d_in[0];     // [4,1024,4096] fp32
    const int* pw    = (const int*)d_in[1];       // [11008*4096/4] int32
    const float* wsc = (const float*)d_in[2];     // [1] fp32

    float* out = (float*)d_out;                   // [4,1024,11008] fp32

    unsigned short* xb = (unsigned short*)d_ws;
    unsigned short* wb = (unsigned short*)((char*)d_ws + (size_t)M_DIM * IN_F * 2);

    // x convert: 16,777,216 elems / 8 per thread
    cvt_x_kernel<<<8192, 256, 0, stream>>>(x, xb);

    // unpack: 11,272,192 packed ints / 4 per thread = 2,818,048 threads
    unpack_w_kernel<<<11008, 256, 0, stream>>>(pw, wb);

    // GEMM: grid (N/128, M/128) = (86, 32)
    gemm_kernel<<<dim3(86, 32), 256, 0, stream>>>(xb, wb, out, wsc);
}

// Round 3
// 680.414 us; speedup vs baseline: 1.3730x; 1.3730x over previous
//
#include <hip/hip_runtime.h>
#include <hip/hip_bf16.h>

// Problem constants
#define OUT_F 11008   // N
#define IN_F  4096    // K
#define M_DIM 4096    // 4 * 1024

typedef __attribute__((ext_vector_type(8))) short bf16x8;          // MFMA A/B frag
typedef __attribute__((ext_vector_type(4))) float f32x4;           // MFMA C/D frag
typedef __attribute__((ext_vector_type(8))) unsigned short us8;    // 16B of bf16 bits

// ---------------------------------------------------------------------------
// Kernel 1: x fp32 -> bf16 (RNE), 8 elems/thread
// ---------------------------------------------------------------------------
__device__ __forceinline__ unsigned short f2bf_rne(float f) {
    unsigned u = __builtin_bit_cast(unsigned, f);
    u += 0x7fffu + ((u >> 16) & 1u);
    return (unsigned short)(u >> 16);
}

__global__ void cvt_x_kernel(const float* __restrict__ x,
                             unsigned short* __restrict__ xb) {
    size_t i = ((size_t)blockIdx.x * blockDim.x + threadIdx.x) * 8;
    float4 a = *(const float4*)(x + i);
    float4 b = *(const float4*)(x + i + 4);
    us8 o;
    o[0] = f2bf_rne(a.x); o[1] = f2bf_rne(a.y);
    o[2] = f2bf_rne(a.z); o[3] = f2bf_rne(a.w);
    o[4] = f2bf_rne(b.x); o[5] = f2bf_rne(b.y);
    o[6] = f2bf_rne(b.z); o[7] = f2bf_rne(b.w);
    *(us8*)(xb + i) = o;
}

// ---------------------------------------------------------------------------
// Kernel 2: unpack 2-bit weights -> bf16 [OUT_F][IN_F] (B^T layout).
// field t in {0,1,2,3} -> t-1 in {-1,0,1,2}; bf16 LUT {0xBF80,0,0x3F80,0x4000}
// ---------------------------------------------------------------------------
__global__ void unpack_w_kernel(const int* __restrict__ pw,
                                unsigned short* __restrict__ wb) {
    size_t i = (size_t)blockIdx.x * blockDim.x + threadIdx.x;
    int4 v = ((const int4*)pw)[i];
    const unsigned long long LUT = 0x40003F800000BF80ull;
    us8 o0, o1;
#pragma unroll
    for (int j = 0; j < 4; j++) {
        o0[j]     = (unsigned short)(LUT >> (((v.x >> (2 * j)) & 3) * 16));
        o0[4 + j] = (unsigned short)(LUT >> (((v.y >> (2 * j)) & 3) * 16));
        o1[j]     = (unsigned short)(LUT >> (((v.z >> (2 * j)) & 3) * 16));
        o1[4 + j] = (unsigned short)(LUT >> (((v.w >> (2 * j)) & 3) * 16));
    }
    ((us8*)wb)[i * 2]     = o0;
    ((us8*)wb)[i * 2 + 1] = o1;
}

// ---------------------------------------------------------------------------
// Kernel 3: bf16 GEMM, C[M][N] = A[M][K] * B[N][K]^T * scale
// 128x128 tile, BK=32, 4 waves 2x2 (64x64 each = 4x4 MFMA 16x16x32 tiles).
//
// LDS: 16-B entry for (row, seg) at index  row*4 + (seg ^ ((row>>1)&3)).
//  - Staging (global_load_lds, forced dst = base + lane*16): instruction for
//    chunk c covers entries [c*64, c*64+64). Lane l holds row = c*16 + l/4,
//    slot = l&3  =>  fetches global seg = (l&3) ^ ((l>>3)&3). Each 4-lane
//    group reads the SAME row's 64 contiguous bytes (seg permutation) ->
//    16 coalesced 64-B transactions per instruction (round-1 efficiency).
//  - Frag read (quad q = lane>>4, mrow = lane&15): 16-B bank-group
//    = 4*(row&1) + q^((mrow>>1)&3) -> each quarter-wave hits all 8 groups
//    exactly twice -> 2-way = conflict-free (m136).
// ---------------------------------------------------------------------------
__global__ __launch_bounds__(256) void gemm_kernel(
    const unsigned short* __restrict__ A,   // [M_DIM][IN_F] bf16 bits
    const unsigned short* __restrict__ B,   // [OUT_F][IN_F] bf16 bits
    float* __restrict__ C,                  // [M_DIM][OUT_F]
    const float* __restrict__ scale_ptr) {
    constexpr int K = IN_F;
    constexpr int N = OUT_F;
    constexpr int NB_N = 86;   // N / 128

    __shared__ unsigned short sA[128 * 32]; // 8 KB
    __shared__ unsigned short sB[128 * 32]; // 8 KB

    const int tid  = threadIdx.x;
    const int wave = tid >> 6;
    const int lane = tid & 63;

    // Column-group swizzle (8 bn per group) for L2 reuse of A across bn.
    const int lin = blockIdx.y * gridDim.x + blockIdx.x;
    const int grp = lin >> 8;                  // / (8*32)
    const int rem = lin & 255;
    const int gw  = (grp * 8 + 8 <= NB_N) ? 8 : (NB_N - grp * 8);
    const int bn  = grp * 8 + rem % gw;
    const int bm  = rem / gw;

    const int wm = (wave >> 1) * 64;
    const int wn = (wave & 1) * 64;

    // staging: lane's row-in-chunk and swizzled k-seg
    const int srow = lane >> 2;                       // 0..15
    const int sseg = (lane & 3) ^ ((lane >> 3) & 3);  // XOR swizzle
    const int scol = sseg * 8;                        // element offset in k

    const unsigned short* Ag = A + (size_t)bm * 128 * K;
    const unsigned short* Bg = B + (size_t)bn * 128 * K;

    f32x4 acc[4][4];
#pragma unroll
    for (int i = 0; i < 4; i++)
#pragma unroll
        for (int j = 0; j < 4; j++) acc[i][j] = (f32x4){0.f, 0.f, 0.f, 0.f};

    const int quad = lane >> 4;   // k-seg for frags, row-quad for C
    const int mrow = lane & 15;   // m (A) / n (B) / col (C)
    const int sw   = quad ^ ((mrow >> 1) & 3);  // frag-read swizzle term

    for (int k0 = 0; k0 < K; k0 += 32) {
        __syncthreads();  // previous tile's frag reads done before overwrite
#pragma unroll
        for (int c = 0; c < 2; c++) {
            const int chunk = wave * 2 + c;
            const int row = chunk * 16 + srow;
            __builtin_amdgcn_global_load_lds(
                (const __attribute__((address_space(1))) void*)(Ag + (size_t)row * K + k0 + scol),
                (__attribute__((address_space(3))) void*)(sA + chunk * 512),
                16, 0, 0);
        }
#pragma unroll
        for (int c = 0; c < 2; c++) {
            const int chunk = wave * 2 + c;
            const int row = chunk * 16 + srow;
            __builtin_amdgcn_global_load_lds(
                (const __attribute__((address_space(1))) void*)(Bg + (size_t)row * K + k0 + scol),
                (__attribute__((address_space(3))) void*)(sB + chunk * 512),
                16, 0, 0);
        }
        __syncthreads();  // staging drained

        bf16x8 af[4], bfg[4];
#pragma unroll
        for (int t = 0; t < 4; t++) {
            const int ra = wm + t * 16 + mrow;
            const int rb = wn + t * 16 + mrow;
            af[t]  = *(const bf16x8*)(sA + (ra * 4 + sw) * 8);
            bfg[t] = *(const bf16x8*)(sB + (rb * 4 + sw) * 8);
        }
#pragma unroll
        for (int i = 0; i < 4; i++)
#pragma unroll
            for (int j = 0; j < 4; j++)
                acc[i][j] = __builtin_amdgcn_mfma_f32_16x16x32_bf16(
                    af[i], bfg[j], acc[i][j], 0, 0, 0);
    }

    // Epilogue: C/D layout col=lane&15, row=quad*4+reg
    const float scale = *scale_ptr;
    float* Cg = C + (size_t)bm * 128 * N + (size_t)bn * 128;
#pragma unroll
    for (int i = 0; i < 4; i++) {
#pragma unroll
        for (int j = 0; j < 4; j++) {
#pragma unroll
            for (int r = 0; r < 4; r++) {
                const int row = wm + i * 16 + quad * 4 + r;
                const int col = wn + j * 16 + mrow;
                Cg[(size_t)row * N + col] = acc[i][j][r] * scale;
            }
        }
    }
}

// ---------------------------------------------------------------------------
// Launch
// ---------------------------------------------------------------------------
extern "C" void kernel_launch(void* const* d_in, const int* in_sizes, int n_in,
                              void* d_out, int out_size, void* d_ws, size_t ws_size,
                              hipStream_t stream) {
    const float* x   = (const float*)d_in[0];     // [4,1024,4096] fp32
    const int* pw    = (const int*)d_in[1];       // [11008*4096/4] int32
    const float* wsc = (const float*)d_in[2];     // [1] fp32

    float* out = (float*)d_out;                   // [4,1024,11008] fp32

    unsigned short* xb = (unsigned short*)d_ws;
    unsigned short* wb = (unsigned short*)((char*)d_ws + (size_t)M_DIM * IN_F * 2);

    // x convert: 16,777,216 elems / 8 per thread
    cvt_x_kernel<<<8192, 256, 0, stream>>>(x, xb);

    // unpack: 11,272,192 packed ints / 4 per thread
    unpack_w_kernel<<<11008, 256, 0, stream>>>(pw, wb);

    // GEMM: grid (N/128, M/128) = (86, 32)
    gemm_kernel<<<dim3(86, 32), 256, 0, stream>>>(xb, wb, out, wsc);
}